// Round 1
// 189.186 us; speedup vs baseline: 1.0485x; 1.0485x over previous
//
#include <hip/hip_runtime.h>
#include <math.h>

// MaskedBalancedBCELoss — hard-negative mining via count-histogram select.
//
// R11: attack k1's latency-serial hot loop. R10's k1 compiled to VGPR=16 —
// the allocator register-minimized the loop (3 float4 loads barely fit),
// leaving ~3 loads in flight/wave. Counters: VALUBusy 8%, hbm 12%, occ 34%,
// bank-conflict negligible -> latency-bound, not BW/VALU/LDS-conflict-bound.
// Changes (k1 only, k5 byte-identical to R10):
//   * unroll grid-stride loop 4x, all 12 float4 loads issued before use
//   * __launch_bounds__(256,4): 128-VGPR budget, still 4 blocks/CU
//   * single-log branch collapse: x = (g!=0 ? p : 1-p); loss identical bitwise
//     to R10's pos/neg_loss_from -> same bins -> midpoint model unchanged
//   * 2-copy LDS histogram (wave parity) to hedge the DS-atomic theory;
//     copies merged exactly at flush. 32.9KB LDS -> still 4 blocks/CU.
// Select stays in its own kernel (R9 lesson: epilogue fusion perturbs the
// hot loop's codegen: VGPR 44, 148us).

#define NBINS1 4096
#define K1_BLOCKS 1024

struct Ctrl {
  unsigned long long pos_cnt;
  unsigned long long neg_cnt;
  unsigned long long k;
  double pos_sum;
  unsigned B;
  unsigned k_rem;
};

#define LN2F 0.69314718055994530942f

__device__ __forceinline__ double bin_mid(unsigned b) {
  return (double)__uint_as_float((b << 19) | 0x40000u);
}

// Per-element processing. Loss value is bit-identical to R10's
// pos_loss_from/neg_loss_from (same expression tree), so bins and the
// midpoint model are unchanged.
__device__ __forceinline__ void proc1(float p, float g, float m,
                                      unsigned& pc, unsigned& nc,
                                      double& psum, unsigned* __restrict__ hc) {
  bool gpos = (g != 0.0f);
  bool valid = (m != 0.0f);
  bool ispos = valid && gpos;
  bool isneg = valid && !gpos;
  float x = gpos ? p : 1.0f - p;
  float loss = -fmaxf(__log2f(x) * LN2F, -100.0f);
  pc += ispos ? 1u : 0u;
  nc += isneg ? 1u : 0u;
  psum += ispos ? (double)loss : 0.0;
  if (isneg) atomicAdd(&hc[__float_as_uint(loss) >> 19], 1u);
}

// ---------------- Kernel 1: reductions + level-1 histogram -----------------
extern "C" __global__ void __launch_bounds__(256, 4)
k1_hist(const float* __restrict__ pred, const float* __restrict__ gt,
        const float* __restrict__ mask, unsigned* __restrict__ hist1,
        Ctrl* __restrict__ ctrl, int n4, int n) {
  __shared__ unsigned h[2][NBINS1];
  for (int i = threadIdx.x; i < 2 * NBINS1; i += blockDim.x)
    ((unsigned*)h)[i] = 0u;
  __syncthreads();

  int wv = threadIdx.x >> 6, ln = threadIdx.x & 63;
  unsigned* hc = h[wv & 1];

  unsigned pc = 0, nc = 0;
  double psum = 0.0;
  const float4* p4 = (const float4*)pred;
  const float4* g4 = (const float4*)gt;
  const float4* m4 = (const float4*)mask;
  int gtid = blockIdx.x * blockDim.x + threadIdx.x;
  int S = gridDim.x * blockDim.x;

  int i = gtid;
  // main: 4 grid-stride steps per iteration, 12 loads issued up front
  for (; i + 3 * S < n4; i += 4 * S) {
    float4 pv0 = p4[i];
    float4 pv1 = p4[i + S];
    float4 pv2 = p4[i + 2 * S];
    float4 pv3 = p4[i + 3 * S];
    float4 gv0 = g4[i];
    float4 gv1 = g4[i + S];
    float4 gv2 = g4[i + 2 * S];
    float4 gv3 = g4[i + 3 * S];
    float4 mv0 = m4[i];
    float4 mv1 = m4[i + S];
    float4 mv2 = m4[i + 2 * S];
    float4 mv3 = m4[i + 3 * S];

    proc1(pv0.x, gv0.x, mv0.x, pc, nc, psum, hc);
    proc1(pv0.y, gv0.y, mv0.y, pc, nc, psum, hc);
    proc1(pv0.z, gv0.z, mv0.z, pc, nc, psum, hc);
    proc1(pv0.w, gv0.w, mv0.w, pc, nc, psum, hc);
    proc1(pv1.x, gv1.x, mv1.x, pc, nc, psum, hc);
    proc1(pv1.y, gv1.y, mv1.y, pc, nc, psum, hc);
    proc1(pv1.z, gv1.z, mv1.z, pc, nc, psum, hc);
    proc1(pv1.w, gv1.w, mv1.w, pc, nc, psum, hc);
    proc1(pv2.x, gv2.x, mv2.x, pc, nc, psum, hc);
    proc1(pv2.y, gv2.y, mv2.y, pc, nc, psum, hc);
    proc1(pv2.z, gv2.z, mv2.z, pc, nc, psum, hc);
    proc1(pv2.w, gv2.w, mv2.w, pc, nc, psum, hc);
    proc1(pv3.x, gv3.x, mv3.x, pc, nc, psum, hc);
    proc1(pv3.y, gv3.y, mv3.y, pc, nc, psum, hc);
    proc1(pv3.z, gv3.z, mv3.z, pc, nc, psum, hc);
    proc1(pv3.w, gv3.w, mv3.w, pc, nc, psum, hc);
  }
  // remainder grid-stride steps
  for (; i < n4; i += S) {
    float4 pv = p4[i], gv = g4[i], mv = m4[i];
    proc1(pv.x, gv.x, mv.x, pc, nc, psum, hc);
    proc1(pv.y, gv.y, mv.y, pc, nc, psum, hc);
    proc1(pv.z, gv.z, mv.z, pc, nc, psum, hc);
    proc1(pv.w, gv.w, mv.w, pc, nc, psum, hc);
  }
  // scalar tail (n % 4 != 0)
  for (int t = n4 * 4 + gtid; t < n; t += S) {
    proc1(pred[t], gt[t], mask[t], pc, nc, psum, hc);
  }

  // block reduce pc/nc/psum
  unsigned long long pcl = pc, ncl = nc;
  for (int off = 32; off > 0; off >>= 1) {
    pcl += __shfl_down(pcl, off);
    ncl += __shfl_down(ncl, off);
    psum += __shfl_down(psum, off);
  }
  __shared__ unsigned long long spc[4], snc[4];
  __shared__ double sps[4];
  if (ln == 0) { spc[wv] = pcl; snc[wv] = ncl; sps[wv] = psum; }
  __syncthreads();   // also ensures all LDS histogram atomics are complete
  if (threadIdx.x == 0) {
    unsigned long long tp = 0, tn = 0; double ts = 0.0;
    for (int w = 0; w < 4; w++) { tp += spc[w]; tn += snc[w]; ts += sps[w]; }
    atomicAdd(&ctrl->pos_cnt, tp);
    atomicAdd(&ctrl->neg_cnt, tn);
    unsafeAtomicAdd(&ctrl->pos_sum, ts);
  }
  // flush merged LDS histogram copies to global (skip empty bins)
  for (int b = threadIdx.x; b < NBINS1; b += blockDim.x) {
    unsigned c = h[0][b] + h[1][b];
    if (c) atomicAdd(&hist1[b], c);
  }
}

// ---------- Kernel 5: select + midpoint neg_sum + output (1 block) ---------
extern "C" __global__ void __launch_bounds__(256)
k5_final(const unsigned* __restrict__ hist1, Ctrl* __restrict__ ctrl,
         float* __restrict__ out) {
  const int T = 256, CH = NBINS1 / T;  // 16 bins per thread
  __shared__ unsigned long long sarr[T];
  __shared__ unsigned long long sk;
  __shared__ unsigned sB, skrem;
  __shared__ double sred[4];
  int t = threadIdx.x;
  int wv = t >> 6, ln = t & 63;

  unsigned cnt[CH];
  unsigned long long tot = 0;
  for (int j = 0; j < CH; j++) { cnt[j] = hist1[t * CH + j]; tot += cnt[j]; }
  sarr[t] = tot;
  if (t == 0) {
    sB = 0xFFFFFFFFu; skrem = 0u;
    unsigned long long pos = ctrl->pos_cnt, negtot = ctrl->neg_cnt;
    unsigned long long k = 0;
    if (pos > 0) {               // FALLBACK_NEG=0 when pos==0
      k = pos * 3ull;            // floor(pos*3.0), exact in integer
      if (k > negtot) k = negtot;
    }
    ctrl->k = k;
    sk = k;
  }
  __syncthreads();
  // inclusive suffix scan: sarr[t] = sum over threads >= t
  for (int off = 1; off < T; off <<= 1) {
    unsigned long long v = (t + off < T) ? sarr[t + off] : 0ull;
    __syncthreads();
    sarr[t] += v;
    __syncthreads();
  }
  unsigned long long k = sk;
  if (k > 0) {
    unsigned long long above = sarr[t] - tot;
    if (above < k && sarr[t] >= k) {
      unsigned long long cum = above;
      for (int j = CH - 1; j >= 0; j--) {
        if (cum + (unsigned long long)cnt[j] >= k) {
          sB = (unsigned)(t * CH + j);
          skrem = (unsigned)(k - cum);
          break;
        }
        cum += cnt[j];
      }
    }
  }
  __syncthreads();
  unsigned B = sB;

  // neg_sum (midpoint model): each thread sums its own bins above B
  double s = 0.0;
  if (B != 0xFFFFFFFFu) {
    for (int j = 0; j < CH; j++) {
      unsigned bi = (unsigned)(t * CH + j);
      if (bi > B && cnt[j]) s += (double)cnt[j] * bin_mid(bi);
    }
  }
  for (int off = 32; off > 0; off >>= 1) s += __shfl_down(s, off);
  if (ln == 0) sred[wv] = s;
  __syncthreads();
  if (t == 0) {
    double neg_sum = sred[0] + sred[1] + sred[2] + sred[3];
    if (skrem > 0 && B != 0xFFFFFFFFu)
      neg_sum += (double)skrem * bin_mid(B);
    double denom = (double)ctrl->pos_cnt + (double)k + 1e-6;
    out[0] = (float)((ctrl->pos_sum + neg_sum) / denom);
  }
}

// ---------------------------------------------------------------------------
extern "C" void kernel_launch(void* const* d_in, const int* in_sizes, int n_in,
                              void* d_out, int out_size, void* d_ws, size_t ws_size,
                              hipStream_t stream) {
  const float* pred = (const float*)d_in[0];
  const float* gt   = (const float*)d_in[1];
  const float* mask = (const float*)d_in[2];
  float* out = (float*)d_out;
  int n = in_sizes[0];
  int n4 = n / 4;
  char* ws = (char*)d_ws;

  // layout: ctrl@0 (64B), hist1@256 (16KB) -> zero first 16640 bytes
  const size_t HIST1_OFF = 256;
  const size_t ZERO_BYTES = HIST1_OFF + NBINS1 * sizeof(unsigned);   // 16640

  Ctrl* ctrl = (Ctrl*)ws;
  unsigned* hist1 = (unsigned*)(ws + HIST1_OFF);

  hipMemsetAsync(d_ws, 0, ZERO_BYTES, stream);
  k1_hist<<<K1_BLOCKS, 256, 0, stream>>>(pred, gt, mask, hist1, ctrl, n4, n);
  k5_final<<<1, 256, 0, stream>>>(hist1, ctrl, out);
}